// Round 18
// baseline (73.121 us; speedup 1.0000x reference)
//
#include <hip/hip_runtime.h>

#define HD 257
#define WD 257
#define NB (8 * HD)    // 2056 (b,y)-row buckets
#define NCHUNK 32      // chunks per batch
#define CAPC 32        // per-(bucket,chunk) slot capacity (lambda~4 -> safe)
#define BPTS 1024      // bin: points per block
#define COUT 64
#define LROW 17        // accum LDS row stride (floats): breaks x*16 bank pattern
#define GPTS 64        // gather: points per block

typedef unsigned int uint;
typedef unsigned short ushort;
typedef short short8 __attribute__((ext_vector_type(8)));
typedef float f32x4 __attribute__((ext_vector_type(4)));
typedef __attribute__((address_space(3))) uint lds_uint;
typedef __attribute__((address_space(1))) const uint gl_uint;

// f32 -> bf16 RNE
__device__ __forceinline__ uint pack_bf16(float a, float b) {
    uint ua = __float_as_uint(a), ub = __float_as_uint(b);
    ua += 0x7fffu + ((ua >> 16) & 1u);
    ub += 0x7fffu + ((ub >> 16) & 1u);
    return (ua >> 16) | (ub & 0xffff0000u);
}
__device__ __forceinline__ unsigned short bf16_1(float a) {
    uint ua = __float_as_uint(a);
    ua += 0x7fffu + ((ua >> 16) & 1u);
    return (unsigned short)(ua >> 16);
}

// K1: bin — NO global atomics, no zero pass (round-15 form). Block (chunk,b):
// LDS histogram of its 1024 points, chunk-local ranks, plain stores. Also
// zeroes the 16B gather zero-buffer each call.
__global__ __launch_bounds__(256) void bin_kernel(
    const float* __restrict__ xyzp,
    uint* __restrict__ cnt2,     // [NB][NCHUNK]
    ushort* __restrict__ pidx,   // [NB][NCHUNK][CAPC] local point idx in batch
    uint* __restrict__ zbuf,     // 16B zero source for gather OOB loads
    int N) {
    __shared__ uint hist[HD];
    const int tid = threadIdx.x;
    const int chunk = blockIdx.x;
    const int b = blockIdx.y;
    const int p0 = chunk * BPTS;
    if (chunk == 0 && b == 0 && tid < 4) zbuf[tid] = 0u;
    for (int i = tid; i < HD; i += 256) hist[i] = 0u;
    __syncthreads();

    const float4* xp = reinterpret_cast<const float4*>(xyzp) + (size_t)b * N;
    uint rec[BPTS / 256];
#pragma unroll
    for (int k = 0; k < BPTS / 256; ++k) {
        int i = p0 + tid + k * 256;
        float4 v = xp[i];
        int y = (int)fminf(fmaxf(rintf(v.y * 256.0f), 0.0f), 256.0f);
        uint r = atomicAdd(&hist[y], 1u);   // LDS only
        rec[k] = (uint)y | (r << 9);
    }
    __syncthreads();

    for (int y = tid; y < HD; y += 256)
        cnt2[(size_t)(b * HD + y) * NCHUNK + chunk] = min(hist[y], (uint)CAPC);

#pragma unroll
    for (int k = 0; k < BPTS / 256; ++k) {
        int y = rec[k] & 511;
        uint r = rec[k] >> 9;
        if (r < CAPC)
            pidx[((size_t)(b * HD + y) * NCHUNK + chunk) * CAPC + r] =
                (ushort)(p0 + tid + k * 256);
    }
}

// K2: accum — round-15 form: one bucket per block (17.5 KB LDS -> 8 blocks/CU),
// predicated slot-grid loop, f32 LDS accumulate, normalize (count = ch0+ch1),
// emit bf16 voxel rows.
__global__ __launch_bounds__(256) void accum_kernel(
    const uint* __restrict__ cnt2,
    const ushort* __restrict__ pidx,
    const float* __restrict__ xyzp,
    const float* __restrict__ feat,
    uint* __restrict__ voxn,       // [S][8] normalized bf16 pairs
    int logN) {
    __shared__ float l[WD * LROW];   // 17476 B
    __shared__ uint pc[NCHUNK];
    const int tid = threadIdx.x;
    const int bucket = blockIdx.x;
    const int b = bucket / HD;       // const-div -> magic mul
    for (int i = tid; i < WD * LROW; i += 256) l[i] = 0.0f;
    if (tid < NCHUNK)
        pc[tid] = cnt2[(size_t)bucket * NCHUNK + tid];
    __syncthreads();

#pragma unroll
    for (int s = 0; s < NCHUNK * CAPC; s += 256) {
        int slot = s + tid;
        int c = slot >> 5;              // chunk: CAPC=32
        int j = slot & (CAPC - 1);
        if ((uint)j < pc[c]) {          // predicated: ~12.5% density
            uint lp = pidx[((size_t)bucket * NCHUNK + c) * CAPC + j];
            int p = (b << logN) + (int)lp;
            float4 v = reinterpret_cast<const float4*>(xyzp)[p];
            int x = (int)fminf(fmaxf(rintf(v.x * 256.0f), 0.0f), 256.0f);
            float* cell = l + x * LROW;
            atomicAdd(&cell[0], v.w);
            atomicAdd(&cell[1], 1.0f - v.w);
            const float2* f2 = reinterpret_cast<const float2*>(feat + (size_t)p * 14);
#pragma unroll
            for (int jj = 0; jj < 7; ++jj) {
                float2 fv = f2[jj];
                atomicAdd(&cell[2 + 2 * jj], fv.x);
                atomicAdd(&cell[3 + 2 * jj], fv.y);
            }
        }
    }
    __syncthreads();

    for (int x = tid; x < WD; x += 256) {
        const float* c = l + x * LROW;
        float inv = __builtin_amdgcn_rcpf(fmaxf(c[0] + c[1], 1.0f));
        uint o[8];
#pragma unroll
        for (int j = 0; j < 8; ++j)
            o[j] = pack_bf16(c[2 * j] * inv, c[2 * j + 1] * inv);
        uint4* op = reinterpret_cast<uint4*>(voxn + ((size_t)bucket * WD + x) * 8);
        op[0] = make_uint4(o[0], o[1], o[2], o[3]);
        op[1] = make_uint4(o[4], o[5], o[6], o[7]);
    }
}

// K3: gather-v5 — A-build via global_load_lds. LDS = 20 slabs x [64 pts x 16B];
// slab = 4s + hi holds k-chunk (kn = 2s+(hi>>1), half = hi&1) for all points.
// Each wave-round: ONE global_load_lds (per-lane scattered src, dest = slab
// base + lane*16). OOB / k>=144 lanes redirect src to zbuf. 5 rounds, 1 barrier.
__global__ __launch_bounds__(256) void gather_mfma_kernel(
    const float* __restrict__ xyzp,
    const uint* __restrict__ voxn,   // [S][8] normalized bf16 pairs
    const uint* __restrict__ zbuf,   // 16B of zeros
    const float* __restrict__ W,     // [9][16][64] f32 = [144][64]
    const float* __restrict__ bias,
    float* __restrict__ out, int logN) {
    __shared__ __align__(16) char sA[20 * 1024];   // 20 KB -> 8 blocks/CU

    const int tid = threadIdx.x;
    const int lane = tid & 63;
    const int w = tid >> 6;
    const int p0 = blockIdx.x * GPTS;
    const int hi = lane >> 4;
    const int lo = lane & 15;

    // per-lane point data (all 4 waves load the same 64 points: L1/L2 hits)
    float4 v = reinterpret_cast<const float4*>(xyzp)[p0 + lane];
    int y = (int)fminf(fmaxf(rintf(v.y * 256.0f), 0.0f), 256.0f);
    int x = (int)fminf(fmaxf(rintf(v.x * 256.0f), 0.0f), 256.0f);
    int b = (p0 + lane) >> logN;
    int cell = (b * HD + y) * WD + x;

    // A-build: 5 rounds x 4 waves = slabs 0..19
#pragma unroll
    for (int r5 = 0; r5 < 5; ++r5) {
        int slab = r5 * 4 + w;               // wave-uniform
        int s_ = slab >> 2, h_ = slab & 3;
        int kn = 2 * s_ + (h_ >> 1);         // 0..9 (9 == zero-pad)
        int half = h_ & 1;
        int seg = kn / 3, kx = kn - 3 * seg; // kn<=8 meaningful
        int ny = y + seg - 1, nx = x + kx - 1;
        bool ok = (kn < 9) && ((uint)ny <= 256u) && ((uint)nx <= 256u);
        const uint* src = ok
            ? voxn + ((size_t)cell + (seg - 1) * WD + (kx - 1)) * 8 + half * 4
            : zbuf;
        __builtin_amdgcn_global_load_lds((gl_uint*)src,
                                         (lds_uint*)(sA + slab * 1024), 16, 0, 0);
    }

    // B fragments (overlap with in-flight LDS loads)
    short8 bfrag[5];
    float bv = bias[w * 16 + lo];
#pragma unroll
    for (int s = 0; s < 5; ++s) {
        int kbase = s * 32 + hi * 8;
        short8 f;
#pragma unroll
        for (int j = 0; j < 8; ++j) {
            int k = kbase + j;
            float wv = (k < 144) ? W[(size_t)k * 64 + w * 16 + lo] : 0.0f;
            f[j] = (short)bf16_1(wv);
        }
        bfrag[s] = f;
    }
    __syncthreads();   // drains vmcnt incl. global_load_lds

    f32x4 acc[4];
#pragma unroll
    for (int mt = 0; mt < 4; ++mt) acc[mt] = (f32x4){bv, bv, bv, bv};

#pragma unroll
    for (int mt = 0; mt < 4; ++mt) {
        const char* abase = sA + hi * 1024 + (mt * 16 + lo) * 16;
#pragma unroll
        for (int s = 0; s < 5; ++s) {
            short8 a = *reinterpret_cast<const short8*>(abase + s * 4096);
            acc[mt] = __builtin_amdgcn_mfma_f32_16x16x32_bf16(a, bfrag[s], acc[mt], 0, 0, 0);
        }
    }

    // store: D col = lane&15, row = hi*4 + reg (m89-verified)
#pragma unroll
    for (int mt = 0; mt < 4; ++mt)
#pragma unroll
        for (int r = 0; r < 4; ++r) {
            int row = mt * 16 + hi * 4 + r;
            out[(size_t)(p0 + row) * 64 + w * 16 + lo] = acc[mt][r];
        }
}

extern "C" void kernel_launch(void* const* d_in, const int* in_sizes, int n_in,
                              void* d_out, int out_size, void* d_ws, size_t ws_size,
                              hipStream_t stream) {
    const float* xyzp = (const float*)d_in[0];
    const float* feat = (const float*)d_in[1];
    const float* W    = (const float*)d_in[2];
    const float* bias = (const float*)d_in[3];
    float* out = (float*)d_out;

    const int BN = in_sizes[0] / 4;  // 262144
    const int B = 8;
    const int N = BN / B;            // 32768
    int logN = 0;
    while ((1 << logN) < N) ++logN;  // 15

    // ws layout: cnt2 | pidx | voxn | zbuf  ~= 21.4 MB
    uint* cnt2 = (uint*)d_ws;                                        // NB*32*4 = 263168 B
    ushort* pidx = (ushort*)((char*)cnt2 + (size_t)NB * NCHUNK * 4); // NB*32*32*2 = 4.21 MB
    uint* voxn = (uint*)((char*)pidx + (size_t)NB * NCHUNK * CAPC * 2);  // 16.9 MB
    uint* zbuf = voxn + (size_t)(B * HD * WD) * 8;                   // 16 B zeros
    (void)ws_size;

    dim3 bgrid(NCHUNK, B);           // 32 x 8
    bin_kernel<<<bgrid, 256, 0, stream>>>(xyzp, cnt2, pidx, zbuf, N);
    accum_kernel<<<NB, 256, 0, stream>>>(cnt2, pidx, xyzp, feat, voxn, logN);
    gather_mfma_kernel<<<BN / GPTS, 256, 0, stream>>>(xyzp, voxn, zbuf, W, bias, out, logN);
}